// Round 20
// baseline (86.040 us; speedup 1.0000x reference)
//
#include <hip/hip_runtime.h>
#include <math.h>

// BlockNet: 4× (unfold-linear ⊕ conv ⊕ sigmoid-gate blend, ReLU) + FC(32->4).
// Round 20: block1_fused13 = v12 + VB=2 (lane computes batches lane, lane+64).
// Evidence: v12 hit 53% occupancy with VALUBusy still 19% -> throughput wall
// in memory pipes, not latency. Each weight ds_read_b128 now feeds 18 FMAs
// (LDS cyc/FMA 2.3 -> 1.16, best of any variant); second batch adds an
// independent dep chain. VGPR ~100 (v12 was 40; 128-cliff is the fail mode).
// Tails unchanged from round 17 (proven).
// CFG: (cin,cout,k,s,oh) = (3,4,5,3,20),(4,6,3,2,9),(6,16,3,2,4),(16,32,3,2,1)

__device__ __forceinline__ float sigmoidf_(float x) {
    return 1.0f / (1.0f + expf(-x));
}

// ---------------------------------------------------------------------------
// block1 fused v13: grid (B/128, 200), 128 threads (2 waves).
// blockIdx.y -> i = y/10 (output row), jp = y%10 (j in {2jp, 2jp+1}).
// lane handles batches b0+lane (A) and b0+64+lane (B). Wave 0 owns phases
// [0,8), wave 1 [8,15); 3 float4 x-window per batch per phase, depth-1
// prefetch. Weights broadcast from LDS. 9-row float4 reduce at the end.
__global__ __launch_bounds__(128)
void block1_fused13(const float* __restrict__ x,     // (B,3,64,64)
                    const float* __restrict__ w_uc,  // (400*75, 4)
                    const float* __restrict__ b_uc,  // (4*400)
                    const float* __restrict__ w_pc,  // (4,75)
                    const float* __restrict__ b_pc,  // (4)
                    const float* __restrict__ w_wl,  // (75)
                    const float* __restrict__ b_wl,  // (1)
                    float* __restrict__ y1t,         // (1600, B)
                    int B)
{
    __shared__ __align__(16) float wu_s[600];       // [jj][n][o], 2-j slice
    __shared__ __align__(16) float wp_s[300];       // [n][o]
    __shared__ float wl_s[75];
    __shared__ __align__(16) float4 red4[9 * 64];   // partials: wave1 -> wave0

    const int tid  = threadIdx.x;                   // 0..127
    const int lane = tid & 63;
    const int wv   = __builtin_amdgcn_readfirstlane(tid >> 6);  // 0..1
    const int b0   = blockIdx.x * 128;
    const int i    = blockIdx.y / 10;               // output row
    const int jp   = blockIdx.y - i * 10;           // j-pair index

    // ---- stage weights once (strided loops; round-7 lesson) ----
    {
        const float4* src = reinterpret_cast<const float4*>(w_uc)
                          + (size_t)(i * 20 + jp * 2) * 75;   // 150 f4
        float4* dst = reinterpret_cast<float4*>(wu_s);
        for (int idx = tid; idx < 150; idx += 128) dst[idx] = src[idx];
        for (int idx = tid; idx < 300; idx += 128)
            wp_s[idx] = w_pc[(idx & 3) * 75 + (idx >> 2)];    // [n][o]
        for (int idx = tid; idx < 75; idx += 128) wl_s[idx] = w_wl[idx];
    }
    __syncthreads();

    float auA[4][2], apA[4][2], agA[2];
    float auB[4][2], apB[4][2], agB[2];
    #pragma unroll
    for (int o = 0; o < 4; ++o)
        #pragma unroll
        for (int jj = 0; jj < 2; ++jj) {
            auA[o][jj] = 0.f; apA[o][jj] = 0.f;
            auB[o][jj] = 0.f; apB[o][jj] = 0.f;
        }
    agA[0] = 0.f; agA[1] = 0.f; agB[0] = 0.f; agB[1] = 0.f;

    // column window: cols [6jp, 6jp+8) needed; aligned start col0, off in {0,2}
    const int colbase = jp * 6;
    const int col0    = colbase & ~3;
    const int off     = colbase & 3;                // 0 or 2
    const float* xbA = x + (size_t)(b0 + lane) * 12288 + (size_t)(i * 3) * 64 + col0;
    const float* xbB = xbA + (size_t)64 * 12288;

    const int p0   = wv ? 8 : 0;
    const int pend = wv ? 15 : 8;

    float4 curA[3], curB[3], nxtA[3], nxtB[3];
    {
        const int c0 = p0 / 5, a0 = p0 - c0 * 5;
        const int roff = c0 * 4096 + a0 * 64;
        #pragma unroll
        for (int q = 0; q < 3; ++q) {
            curA[q] = *reinterpret_cast<const float4*>(xbA + roff + q * 4);
            curB[q] = *reinterpret_cast<const float4*>(xbB + roff + q * 4);
        }
    }

    #pragma unroll 1
    for (int p = p0; p < pend; ++p) {
        // ---- A) prefetch next phase's x (both batches) ----
        if (p + 1 < pend) {
            const int pn = p + 1;
            const int cn = pn / 5;
            const int an = pn - cn * 5;
            const int roff = cn * 4096 + an * 64;
            #pragma unroll
            for (int q = 0; q < 3; ++q) {
                nxtA[q] = *reinterpret_cast<const float4*>(xbA + roff + q * 4);
                nxtB[q] = *reinterpret_cast<const float4*>(xbB + roff + q * 4);
            }
        }

        // ---- B) unpack cur with wave-uniform constant offset ----
        float cfA[12], cfB[12];
        #pragma unroll
        for (int q = 0; q < 3; ++q) {
            cfA[4 * q + 0] = curA[q].x; cfA[4 * q + 1] = curA[q].y;
            cfA[4 * q + 2] = curA[q].z; cfA[4 * q + 3] = curA[q].w;
            cfB[4 * q + 0] = curB[q].x; cfB[4 * q + 1] = curB[q].y;
            cfB[4 * q + 2] = curB[q].z; cfB[4 * q + 3] = curB[q].w;
        }
        float xvA[8], xvB[8];
        if (off == 0) {
            #pragma unroll
            for (int t = 0; t < 8; ++t) { xvA[t] = cfA[t]; xvB[t] = cfB[t]; }
        } else {
            #pragma unroll
            for (int t = 0; t < 8; ++t) { xvA[t] = cfA[t + 2]; xvB[t] = cfB[t + 2]; }
        }

        // ---- C) 10 taps (2 j x 5 b2) x 2 batches, weights from LDS ----
        const int n0 = p * 5;                       // = c*25 + a*5
        #pragma unroll
        for (int b2 = 0; b2 < 5; ++b2) {
            const float  wlv = wl_s[n0 + b2];
            const float4 wp4 = *reinterpret_cast<const float4*>(&wp_s[(n0 + b2) * 4]);
            #pragma unroll
            for (int jj = 0; jj < 2; ++jj) {
                const float4 w4 = *reinterpret_cast<const float4*>(
                    &wu_s[(jj * 75 + n0 + b2) * 4]);
                const float vA = xvA[3 * jj + b2];
                const float vB = xvB[3 * jj + b2];
                agA[jj]    += vA * wlv;   agB[jj]    += vB * wlv;
                auA[0][jj] += vA * w4.x;  auB[0][jj] += vB * w4.x;
                auA[1][jj] += vA * w4.y;  auB[1][jj] += vB * w4.y;
                auA[2][jj] += vA * w4.z;  auB[2][jj] += vB * w4.z;
                auA[3][jj] += vA * w4.w;  auB[3][jj] += vB * w4.w;
                apA[0][jj] += vA * wp4.x; apB[0][jj] += vB * wp4.x;
                apA[1][jj] += vA * wp4.y; apB[1][jj] += vB * wp4.y;
                apA[2][jj] += vA * wp4.z; apB[2][jj] += vB * wp4.z;
                apA[3][jj] += vA * wp4.w; apB[3][jj] += vB * wp4.w;
            }
        }

        // ---- D) rotate ----
        if (p + 1 < pend) {
            #pragma unroll
            for (int q = 0; q < 3; ++q) { curA[q] = nxtA[q]; curB[q] = nxtB[q]; }
        }
    }

    // ---- reduce: wave 1 publishes partials, wave 0 combines + epilogue ----
    if (wv == 1) {
        red4[0 * 64 + lane] = make_float4(auA[0][0], auA[1][0], auA[2][0], auA[3][0]);
        red4[1 * 64 + lane] = make_float4(auA[0][1], auA[1][1], auA[2][1], auA[3][1]);
        red4[2 * 64 + lane] = make_float4(apA[0][0], apA[1][0], apA[2][0], apA[3][0]);
        red4[3 * 64 + lane] = make_float4(apA[0][1], apA[1][1], apA[2][1], apA[3][1]);
        red4[4 * 64 + lane] = make_float4(auB[0][0], auB[1][0], auB[2][0], auB[3][0]);
        red4[5 * 64 + lane] = make_float4(auB[0][1], auB[1][1], auB[2][1], auB[3][1]);
        red4[6 * 64 + lane] = make_float4(apB[0][0], apB[1][0], apB[2][0], apB[3][0]);
        red4[7 * 64 + lane] = make_float4(apB[0][1], apB[1][1], apB[2][1], apB[3][1]);
        red4[8 * 64 + lane] = make_float4(agA[0], agA[1], agB[0], agB[1]);
    }
    __syncthreads();
    if (wv == 0) {
        {
            const float4 t0 = red4[0 * 64 + lane];
            auA[0][0] += t0.x; auA[1][0] += t0.y; auA[2][0] += t0.z; auA[3][0] += t0.w;
            const float4 t1 = red4[1 * 64 + lane];
            auA[0][1] += t1.x; auA[1][1] += t1.y; auA[2][1] += t1.z; auA[3][1] += t1.w;
            const float4 t2 = red4[2 * 64 + lane];
            apA[0][0] += t2.x; apA[1][0] += t2.y; apA[2][0] += t2.z; apA[3][0] += t2.w;
            const float4 t3 = red4[3 * 64 + lane];
            apA[0][1] += t3.x; apA[1][1] += t3.y; apA[2][1] += t3.z; apA[3][1] += t3.w;
            const float4 t4 = red4[4 * 64 + lane];
            auB[0][0] += t4.x; auB[1][0] += t4.y; auB[2][0] += t4.z; auB[3][0] += t4.w;
            const float4 t5 = red4[5 * 64 + lane];
            auB[0][1] += t5.x; auB[1][1] += t5.y; auB[2][1] += t5.z; auB[3][1] += t5.w;
            const float4 t6 = red4[6 * 64 + lane];
            apB[0][0] += t6.x; apB[1][0] += t6.y; apB[2][0] += t6.z; apB[3][0] += t6.w;
            const float4 t7 = red4[7 * 64 + lane];
            apB[0][1] += t7.x; apB[1][1] += t7.y; apB[2][1] += t7.z; apB[3][1] += t7.w;
            const float4 t8 = red4[8 * 64 + lane];
            agA[0] += t8.x; agA[1] += t8.y; agB[0] += t8.z; agB[1] += t8.w;
        }

        const float bwl = b_wl[0];
        #pragma unroll
        for (int jj = 0; jj < 2; ++jj) {
            const int l = i * 20 + jp * 2 + jj;
            const float gA = sigmoidf_(agA[jj] + bwl);
            const float gB = sigmoidf_(agB[jj] + bwl);
            #pragma unroll
            for (int o = 0; o < 4; ++o) {
                const float buc = b_uc[o * 400 + l];
                const float bpc = b_pc[o];
                const float yA = (auA[o][jj] + buc) * gA
                               + (apA[o][jj] + bpc) * (1.f - gA);
                const float yB = (auB[o][jj] + buc) * gB
                               + (apB[o][jj] + bpc) * (1.f - gB);
                float* dst = y1t + (size_t)(o * 400 + l) * B + b0;
                dst[lane]      = fmaxf(yA, 0.f);
                dst[64 + lane] = fmaxf(yB, 0.f);
            }
        }
    }
}

// ------------- batch-last block kernel: wave owns one location l ----------
template<int CIN, int COUT, int K, int S, int OH, int IH, int VB>
__global__ __launch_bounds__(256)
void blockT_kernel(const float* __restrict__ in_t,
                   const float* __restrict__ w_uc,  // (L*LN, COUT)
                   const float* __restrict__ b_uc,  // (COUT*L)
                   const float* __restrict__ w_pc,  // (COUT, LN)
                   const float* __restrict__ b_pc,  // (COUT)
                   const float* __restrict__ w_wl,  // (LN)
                   const float* __restrict__ b_wl,  // (1)
                   float* __restrict__ out_t,
                   int B)
{
    constexpr int LN = CIN * K * K;
    constexpr int L  = OH * OH;
    const int wv   = threadIdx.x >> 6;
    const int lane = threadIdx.x & 63;
    const int l    = __builtin_amdgcn_readfirstlane(blockIdx.y * 4 + wv);
    if (l >= L) return;
    const int i = l / OH, j = l % OH;
    const int b = blockIdx.x * (64 * VB) + lane * VB;

    float au[COUT][VB], ap[COUT][VB], ag[VB];
    #pragma unroll
    for (int o = 0; o < COUT; ++o)
        #pragma unroll
        for (int q = 0; q < VB; ++q) { au[o][q] = 0.f; ap[o][q] = 0.f; }
    #pragma unroll
    for (int q = 0; q < VB; ++q) ag[q] = 0.f;

    const float* wu = w_uc + (size_t)l * LN * COUT;

    #pragma unroll
    for (int c = 0; c < CIN; ++c)
    #pragma unroll
    for (int a = 0; a < K; ++a)
    #pragma unroll
    for (int b2 = 0; b2 < K; ++b2) {
        const int n = c * K * K + a * K + b2;
        const int p = c * IH * IH + (i * S + a) * IH + (j * S + b2);
        float v[VB];
        const float* src = in_t + (size_t)p * B + b;
        if constexpr (VB == 4) {
            const float4 t = *reinterpret_cast<const float4*>(src);
            v[0] = t.x; v[1] = t.y; v[2] = t.z; v[3] = t.w;
        } else if constexpr (VB == 2) {
            const float2 t = *reinterpret_cast<const float2*>(src);
            v[0] = t.x; v[1] = t.y;
        } else {
            v[0] = src[0];
        }
        const float wl = w_wl[n];
        #pragma unroll
        for (int q = 0; q < VB; ++q) ag[q] += v[q] * wl;
        #pragma unroll
        for (int o = 0; o < COUT; ++o) {
            const float wuv = wu[n * COUT + o];
            const float wpv = w_pc[o * LN + n];
            #pragma unroll
            for (int q = 0; q < VB; ++q) {
                au[o][q] += v[q] * wuv;
                ap[o][q] += v[q] * wpv;
            }
        }
    }

    const float bwl = b_wl[0];
    float g[VB];
    #pragma unroll
    for (int q = 0; q < VB; ++q) g[q] = sigmoidf_(ag[q] + bwl);

    #pragma unroll
    for (int o = 0; o < COUT; ++o) {
        const float buc = b_uc[o * L + l];
        const float bpc = b_pc[o];
        float y[VB];
        #pragma unroll
        for (int q = 0; q < VB; ++q) {
            const float x1 = au[o][q] + buc;
            const float x2 = ap[o][q] + bpc;
            y[q] = fmaxf(x1 * g[q] + x2 * (1.f - g[q]), 0.f);
        }
        float* dst = out_t + (size_t)(o * L + l) * B + b;
        if constexpr (VB == 4) {
            float4 t; t.x = y[0]; t.y = y[1]; t.z = y[2]; t.w = y[3];
            *reinterpret_cast<float4*>(dst) = t;
        } else if constexpr (VB == 2) {
            float2 t; t.x = y[0]; t.y = y[1];
            *reinterpret_cast<float2*>(dst) = t;
        } else {
            dst[0] = y[0];
        }
    }
}

// ---------- block3 split-channel: cin=6,cout=16,k=3,s=2,oh=4,ih=9 ----------
__global__ __launch_bounds__(256)
void block3T_split(const float* __restrict__ in_t,  // (486, B)
                   const float* __restrict__ w_uc,  // (16*54, 16)
                   const float* __restrict__ b_uc,  // (16*16)
                   const float* __restrict__ w_pc,  // (16, 54)
                   const float* __restrict__ b_pc,  // (16)
                   const float* __restrict__ w_wl,  // (54)
                   const float* __restrict__ b_wl,  // (1)
                   float* __restrict__ out_t,       // (256, B)
                   int B)
{
    __shared__ __align__(16) float4 red4[2][9][64];

    const int tid   = threadIdx.x;
    const int lane  = tid & 63;
    const int w     = __builtin_amdgcn_readfirstlane(tid >> 6);  // 0..3
    const int lslot = w >> 1;
    const int chalf = w & 1;
    const int l     = blockIdx.y * 2 + lslot;        // 0..15
    const int i     = l >> 2, j = l & 3;
    const int b     = blockIdx.x * 64 + lane;

    float au[16], ap[16], ag = 0.f;
    #pragma unroll
    for (int o = 0; o < 16; ++o) { au[o] = 0.f; ap[o] = 0.f; }

    const float* wu = w_uc + (size_t)l * 54 * 16;
    #pragma unroll
    for (int cc = 0; cc < 3; ++cc) {
        const int c = chalf * 3 + cc;
        #pragma unroll
        for (int a = 0; a < 3; ++a)
        #pragma unroll
        for (int b2 = 0; b2 < 3; ++b2) {
            const int n = c * 9 + a * 3 + b2;
            const int p = c * 81 + (i * 2 + a) * 9 + (j * 2 + b2);
            const float v = in_t[(size_t)p * B + b];
            ag += v * w_wl[n];
            #pragma unroll
            for (int o = 0; o < 16; ++o) {
                au[o] += v * wu[n * 16 + o];
                ap[o] += v * w_pc[o * 54 + n];
            }
        }
    }

    if (chalf == 1) {
        #pragma unroll
        for (int q = 0; q < 4; ++q) {
            red4[lslot][q][lane] =
                make_float4(au[4*q], au[4*q+1], au[4*q+2], au[4*q+3]);
            red4[lslot][4 + q][lane] =
                make_float4(ap[4*q], ap[4*q+1], ap[4*q+2], ap[4*q+3]);
        }
        red4[lslot][8][lane] = make_float4(ag, 0.f, 0.f, 0.f);
    }
    __syncthreads();
    if (chalf == 0) {
        #pragma unroll
        for (int q = 0; q < 4; ++q) {
            const float4 tu = red4[lslot][q][lane];
            au[4*q] += tu.x; au[4*q+1] += tu.y; au[4*q+2] += tu.z; au[4*q+3] += tu.w;
            const float4 tp = red4[lslot][4 + q][lane];
            ap[4*q] += tp.x; ap[4*q+1] += tp.y; ap[4*q+2] += tp.z; ap[4*q+3] += tp.w;
        }
        ag += red4[lslot][8][lane].x;

        const float g = sigmoidf_(ag + b_wl[0]);
        #pragma unroll
        for (int o = 0; o < 16; ++o) {
            const float x1 = au[o] + b_uc[o * 16 + l];
            const float x2 = ap[o] + b_pc[o];
            out_t[(size_t)(o * 16 + l) * B + b] =
                fmaxf(x1 * g + x2 * (1.f - g), 0.f);
        }
    }
}

// ---------- block4 (cin=16,k=3,s=2,oh=1,cout=32) + FC(32->4), batch-last ---
__global__ __launch_bounds__(256)
void block4T_fc(const float* __restrict__ in_t,  // (256, B)
                const float* __restrict__ w_uc,  // (144,32)
                const float* __restrict__ b_uc,  // (32)
                const float* __restrict__ w_pc,  // (32,144)
                const float* __restrict__ b_pc,  // (32)
                const float* __restrict__ w_wl,  // (144)
                const float* __restrict__ b_wl,  // (1)
                const float* __restrict__ fc_w,  // (32,4)
                const float* __restrict__ fc_b,  // (4)
                float* __restrict__ out,         // (B,4)
                int B)
{
    __shared__ __align__(16) float wu_s[144 * 36];
    __shared__ __align__(16) float wp_s[144 * 36];
    __shared__ float wl_s[144];
    __shared__ float buc_s[32], bpc_s[32], fcw_s[128], fcb_s[4];
    __shared__ float red[4][64][5];

    const int tid  = threadIdx.x;
    const int wv   = tid >> 6;
    const int lane = tid & 63;
    const int o0   = __builtin_amdgcn_readfirstlane(wv * 8);
    const int b    = blockIdx.x * 64 + lane;

    for (int idx = tid; idx < 144 * 32; idx += 256) {
        wu_s[(idx >> 5) * 36 + (idx & 31)] = w_uc[idx];
        const int o = idx / 144, n = idx - o * 144;
        wp_s[n * 36 + o] = w_pc[idx];
    }
    if (tid < 144) wl_s[tid] = w_wl[tid];
    if (tid < 32)  { buc_s[tid] = b_uc[tid]; bpc_s[tid] = b_pc[tid]; }
    if (tid >= 64 && tid < 192) fcw_s[tid - 64] = fc_w[tid - 64];
    if (tid >= 192 && tid < 196) fcb_s[tid - 192] = fc_b[tid - 192];
    __syncthreads();

    float au[8], apc[8], ag = 0.f;
    #pragma unroll
    for (int oo = 0; oo < 8; ++oo) { au[oo] = 0.f; apc[oo] = 0.f; }

    #pragma unroll
    for (int c = 0; c < 16; ++c) {
        float v[9];
        #pragma unroll
        for (int a = 0; a < 3; ++a)
        #pragma unroll
        for (int b2 = 0; b2 < 3; ++b2)
            v[a * 3 + b2] = in_t[(size_t)(c * 16 + a * 4 + b2) * B + b];

        #pragma unroll
        for (int t = 0; t < 9; ++t) {
            const int n = c * 9 + t;
            ag += v[t] * wl_s[n];
            const float4 wuA = *reinterpret_cast<const float4*>(&wu_s[n * 36 + o0]);
            const float4 wuB = *reinterpret_cast<const float4*>(&wu_s[n * 36 + o0 + 4]);
            const float4 wpA = *reinterpret_cast<const float4*>(&wp_s[n * 36 + o0]);
            const float4 wpB = *reinterpret_cast<const float4*>(&wp_s[n * 36 + o0 + 4]);
            au[0] += v[t] * wuA.x;  au[1] += v[t] * wuA.y;
            au[2] += v[t] * wuA.z;  au[3] += v[t] * wuA.w;
            au[4] += v[t] * wuB.x;  au[5] += v[t] * wuB.y;
            au[6] += v[t] * wuB.z;  au[7] += v[t] * wuB.w;
            apc[0] += v[t] * wpA.x; apc[1] += v[t] * wpA.y;
            apc[2] += v[t] * wpA.z; apc[3] += v[t] * wpA.w;
            apc[4] += v[t] * wpB.x; apc[5] += v[t] * wpB.y;
            apc[6] += v[t] * wpB.z; apc[7] += v[t] * wpB.w;
        }
    }

    const float g = sigmoidf_(ag + b_wl[0]);
    float pf[4] = {0.f, 0.f, 0.f, 0.f};
    #pragma unroll
    for (int oo = 0; oo < 8; ++oo) {
        const int o = o0 + oo;
        const float h = fmaxf((au[oo] + buc_s[o]) * g +
                              (apc[oo] + bpc_s[o]) * (1.f - g), 0.f);
        #pragma unroll
        for (int f = 0; f < 4; ++f) pf[f] += h * fcw_s[o * 4 + f];
    }
    #pragma unroll
    for (int f = 0; f < 4; ++f) red[wv][lane][f] = pf[f];
    __syncthreads();
    if (wv == 0) {
        float4 s;
        s.x = fcb_s[0] + red[0][lane][0] + red[1][lane][0] + red[2][lane][0] + red[3][lane][0];
        s.y = fcb_s[1] + red[0][lane][1] + red[1][lane][1] + red[2][lane][1] + red[3][lane][1];
        s.z = fcb_s[2] + red[0][lane][2] + red[1][lane][2] + red[2][lane][2] + red[3][lane][2];
        s.w = fcb_s[3] + red[0][lane][3] + red[1][lane][3] + red[2][lane][3] + red[3][lane][3];
        *reinterpret_cast<float4*>(out + (size_t)b * 4) = s;
    }
}

// ======================= fallback path (round-1, NCHW) ====================
template<int CIN, int COUT, int K, int S, int OH, int IH, int BPB>
__global__ __launch_bounds__(256)
void block_kernel(const float* __restrict__ in,
                  const float* __restrict__ w_uc,
                  const float* __restrict__ b_uc,
                  const float* __restrict__ w_pc,
                  const float* __restrict__ b_pc,
                  const float* __restrict__ w_wl,
                  const float* __restrict__ b_wl,
                  float* __restrict__ out,
                  int B)
{
    constexpr int LN   = CIN * K * K;
    constexpr int L    = OH * OH;
    constexpr int TILE = CIN * IH * IH;
    __shared__ __align__(16) float lds[BPB * TILE];

    const int b0 = blockIdx.x * BPB;
    const int nb = (B - b0 < BPB) ? (B - b0) : BPB;
    const int tot = nb * TILE;
    const float* src = in + (size_t)b0 * TILE;
    if ((tot & 3) == 0) {
        const float4* s4 = reinterpret_cast<const float4*>(src);
        float4* d4 = reinterpret_cast<float4*>(lds);
        for (int idx = threadIdx.x; idx < (tot >> 2); idx += blockDim.x) d4[idx] = s4[idx];
    } else {
        for (int idx = threadIdx.x; idx < tot; idx += blockDim.x) lds[idx] = src[idx];
    }
    __syncthreads();

    const float bwl = b_wl[0];
    for (int t = threadIdx.x; t < nb * L; t += blockDim.x) {
        const int bb = t / L;
        const int l  = t % L;
        const int i  = l / OH, j = l % OH;
        const float* tile = lds + bb * TILE;

        float acc_uc[COUT], acc_pc[COUT];
        #pragma unroll
        for (int o = 0; o < COUT; ++o) { acc_uc[o] = 0.f; acc_pc[o] = 0.f; }
        float acc_g = 0.f;

        const float* wu = w_uc + (size_t)l * LN * COUT;
        #pragma unroll
        for (int c = 0; c < CIN; ++c)
        #pragma unroll
        for (int a = 0; a < K; ++a)
        #pragma unroll
        for (int b2 = 0; b2 < K; ++b2) {
            const int n = c * K * K + a * K + b2;
            const float v = tile[c * IH * IH + (i * S + a) * IH + (j * S + b2)];
            acc_g += v * w_wl[n];
            #pragma unroll
            for (int o = 0; o < COUT; ++o) acc_uc[o] += v * wu[n * COUT + o];
            #pragma unroll
            for (int o = 0; o < COUT; ++o) acc_pc[o] += v * w_pc[o * LN + n];
        }

        const float g = sigmoidf_(acc_g + bwl);
        const size_t ob = (size_t)(b0 + bb) * COUT * L;
        #pragma unroll
        for (int o = 0; o < COUT; ++o) {
            const float x1 = acc_uc[o] + b_uc[o * L + l];
            const float x2 = acc_pc[o] + b_pc[o];
            out[ob + o * L + l] = fmaxf(x1 * g + x2 * (1.f - g), 0.f);
        }
    }
}

__global__ __launch_bounds__(256)
void block4_fc_kernel(const float* __restrict__ in,
                      const float* __restrict__ w_uc,
                      const float* __restrict__ b_uc,
                      const float* __restrict__ w_pc,
                      const float* __restrict__ b_pc,
                      const float* __restrict__ w_wl,
                      const float* __restrict__ b_wl,
                      const float* __restrict__ fc_w,
                      const float* __restrict__ fc_b,
                      float* __restrict__ out,
                      int B)
{
    __shared__ float hbuf[8][32];
    const int bl = threadIdx.x >> 5;
    const int o  = threadIdx.x & 31;
    const int b  = blockIdx.x * 8 + bl;

    if (b < B) {
        const float* xb = in + (size_t)b * 256;
        float acc_uc = 0.f, acc_pc = 0.f, acc_g = 0.f;
        #pragma unroll
        for (int c = 0; c < 16; ++c)
        #pragma unroll
        for (int a = 0; a < 3; ++a)
        #pragma unroll
        for (int b2 = 0; b2 < 3; ++b2) {
            const int n = c * 9 + a * 3 + b2;
            const float v = xb[c * 16 + a * 4 + b2];
            acc_uc += v * w_uc[n * 32 + o];
            acc_pc += v * w_pc[o * 144 + n];
            acc_g  += v * w_wl[n];
        }
        const float g  = sigmoidf_(acc_g + b_wl[0]);
        hbuf[bl][o] = fmaxf((acc_uc + b_uc[o]) * g + (acc_pc + b_pc[o]) * (1.f - g), 0.f);
    }
    __syncthreads();

    if (threadIdx.x < 32) {
        const int bl2 = threadIdx.x >> 2;
        const int f   = threadIdx.x & 3;
        const int bb  = blockIdx.x * 8 + bl2;
        if (bb < B) {
            float s = fc_b[f];
            #pragma unroll
            for (int oo = 0; oo < 32; ++oo) s += hbuf[bl2][oo] * fc_w[oo * 4 + f];
            out[(size_t)bb * 4 + f] = s;
        }
    }
}

// ==========================================================================
extern "C" void kernel_launch(void* const* d_in, const int* in_sizes, int n_in,
                              void* d_out, int out_size, void* d_ws, size_t ws_size,
                              hipStream_t stream) {
    const float* x    = (const float*)d_in[0];
    const float* wuc1 = (const float*)d_in[1];
    const float* buc1 = (const float*)d_in[2];
    const float* wpc1 = (const float*)d_in[3];
    const float* bpc1 = (const float*)d_in[4];
    const float* wwl1 = (const float*)d_in[5];
    const float* bwl1 = (const float*)d_in[6];
    const float* wuc2 = (const float*)d_in[7];
    const float* buc2 = (const float*)d_in[8];
    const float* wpc2 = (const float*)d_in[9];
    const float* bpc2 = (const float*)d_in[10];
    const float* wwl2 = (const float*)d_in[11];
    const float* bwl2 = (const float*)d_in[12];
    const float* wuc3 = (const float*)d_in[13];
    const float* buc3 = (const float*)d_in[14];
    const float* wpc3 = (const float*)d_in[15];
    const float* bpc3 = (const float*)d_in[16];
    const float* wwl3 = (const float*)d_in[17];
    const float* bwl3 = (const float*)d_in[18];
    const float* wuc4 = (const float*)d_in[19];
    const float* buc4 = (const float*)d_in[20];
    const float* wpc4 = (const float*)d_in[21];
    const float* bpc4 = (const float*)d_in[22];
    const float* wwl4 = (const float*)d_in[23];
    const float* bwl4 = (const float*)d_in[24];
    const float* fcw  = (const float*)d_in[25];
    const float* fcb  = (const float*)d_in[26];

    const int B = in_sizes[0] / (3 * 64 * 64);   // 2048
    float* ws = (float*)d_ws;
    const size_t need = sizeof(float) * (size_t)(1600 + 486 + 256) * B;

    if (ws_size >= need && (B % 256) == 0) {
        // ---------------- batch-last fast path ----------------
        float* y1 = ws;                             // (1600, B)
        float* y2 = y1 + (size_t)1600 * B;          // (486, B)
        float* y3 = y2 + (size_t)486 * B;           // (256, B)

        block1_fused13<<<dim3(B / 128, 200), 128, 0, stream>>>(
            x, wuc1, buc1, wpc1, bpc1, wwl1, bwl1, y1, B);
        blockT_kernel<4, 6, 3, 2, 9, 20, 1>
            <<<dim3(B / 64, 21), 256, 0, stream>>>(y1, wuc2, buc2, wpc2, bpc2, wwl2, bwl2, y2, B);
        block3T_split<<<dim3(B / 64, 8), 256, 0, stream>>>(
            y2, wuc3, buc3, wpc3, bpc3, wwl3, bwl3, y3, B);
        block4T_fc<<<B / 64, 256, 0, stream>>>(y3, wuc4, buc4, wpc4, bpc4, wwl4, bwl4,
                                               fcw, fcb, (float*)d_out, B);
    } else {
        // ---------------- fallback (round-1) ----------------
        float* y1 = ws;
        float* y2 = y1 + (size_t)B * 4 * 400;
        float* y3 = y2 + (size_t)B * 6 * 81;
        block_kernel<3, 4, 5, 3, 20, 64, 1>
            <<<B, 256, 0, stream>>>(x, wuc1, buc1, wpc1, bpc1, wwl1, bwl1, y1, B);
        block_kernel<4, 6, 3, 2, 9, 20, 4>
            <<<(B + 3) / 4, 256, 0, stream>>>(y1, wuc2, buc2, wpc2, bpc2, wwl2, bwl2, y2, B);
        block_kernel<6, 16, 3, 2, 4, 9, 16>
            <<<(B + 15) / 16, 256, 0, stream>>>(y2, wuc3, buc3, wpc3, bpc3, wwl3, bwl3, y3, B);
        block4_fc_kernel<<<(B + 7) / 8, 256, 0, stream>>>(
            y3, wuc4, buc4, wpc4, bpc4, wwl4, bwl4, fcw, fcb, (float*)d_out, B);
    }
}

// Round 21
// 78.726 us; speedup vs baseline: 1.0929x; 1.0929x over previous
//
#include <hip/hip_runtime.h>
#include <math.h>

// BlockNet: 4× (unfold-linear ⊕ conv ⊕ sigmoid-gate blend, ReLU) + FC(32->4).
// Round 21: RESTORE round-17's best-measured configuration (78.8 µs).
// block1_fused9 (round-14 v9, 64 µs: 2-wave phase split, depth-1 prefetch,
// VGPR 68) + fast tails (blockT2 VB=1, block3T_split, block4T_fc).
// Evidence for stopping here: VALUBusy pinned at 18.4-19% across 8 block1
// variants spanning occupancy 14-53%, VGPR 40-256, coalesced/uncoalesced —
// per-instruction-proportional overhead, not fixable by splitting/occupancy.
// CFG: (cin,cout,k,s,oh) = (3,4,5,3,20),(4,6,3,2,9),(6,16,3,2,4),(16,32,3,2,1)

__device__ __forceinline__ float sigmoidf_(float x) {
    return 1.0f / (1.0f + expf(-x));
}

// ---------------------------------------------------------------------------
// block1 fused v9: grid (B/64, 80), 128 threads (2 waves).
// blockIdx.y -> i = y>>2 (output row), jgroup = y&3 (j in [5jg, 5jg+5)).
// lane = batch. Wave 0 owns phases [0,8), wave 1 [8,15); each lane loads its
// own batch's 20-col window per phase (5 aligned float4), prefetched 1 phase
// ahead in registers. Weights broadcast from LDS. One reduce at the end.
__global__ __launch_bounds__(128)
void block1_fused9(const float* __restrict__ x,     // (B,3,64,64)
                   const float* __restrict__ w_uc,  // (400*75, 4)
                   const float* __restrict__ b_uc,  // (4*400)
                   const float* __restrict__ w_pc,  // (4,75)
                   const float* __restrict__ b_pc,  // (4)
                   const float* __restrict__ w_wl,  // (75)
                   const float* __restrict__ b_wl,  // (1)
                   float* __restrict__ y1t,         // (1600, B)
                   int B)
{
    __shared__ __align__(16) float wu_s[1500];      // [jj][n][o], 5-j slice
    __shared__ __align__(16) float wp_s[300];       // [n][o]
    __shared__ float wl_s[75];
    __shared__ __align__(16) float4 red4[12 * 64];  // partials: wave1 -> wave0

    const int tid  = threadIdx.x;                   // 0..127
    const int lane = tid & 63;
    const int wv   = __builtin_amdgcn_readfirstlane(tid >> 6);  // 0..1
    const int b0   = blockIdx.x * 64;
    const int i    = blockIdx.y >> 2;               // output row
    const int jgroup = blockIdx.y & 3;              // j-quintet

    // ---- stage weights once (strided loops; round-7 lesson) ----
    {
        const float4* src = reinterpret_cast<const float4*>(w_uc)
                          + (size_t)(i * 20 + jgroup * 5) * 75;   // 375 f4
        float4* dst = reinterpret_cast<float4*>(wu_s);
        for (int idx = tid; idx < 375; idx += 128) dst[idx] = src[idx];
        for (int idx = tid; idx < 300; idx += 128)
            wp_s[idx] = w_pc[(idx & 3) * 75 + (idx >> 2)];        // [n][o]
        for (int idx = tid; idx < 75; idx += 128) wl_s[idx] = w_wl[idx];
    }
    __syncthreads();

    float au[4][5], ap[4][5], ag[5];
    #pragma unroll
    for (int o = 0; o < 4; ++o)
        #pragma unroll
        for (int jj = 0; jj < 5; ++jj) { au[o][jj] = 0.f; ap[o][jj] = 0.f; }
    #pragma unroll
    for (int jj = 0; jj < 5; ++jj) ag[jj] = 0.f;

    // per-jgroup column window (cols [15jg, 15jg+17) within aligned 20)
    const int col0 = (jgroup == 0) ? 0 : (jgroup == 1) ? 12
                   : (jgroup == 2) ? 28 : 44;
    const int off  = jgroup * 15 - col0;            // {0,3,2,1}
    const float* xb = x + (size_t)(b0 + lane) * 12288 + (size_t)(i * 3) * 64 + col0;

    const int p0   = wv ? 8 : 0;
    const int pend = wv ? 15 : 8;

    float4 cur[5], nxt[5];
    {
        const int c0 = p0 / 5, a0 = p0 - c0 * 5;
        const float* s0 = xb + c0 * 4096 + a0 * 64;
        #pragma unroll
        for (int q = 0; q < 5; ++q)
            cur[q] = *reinterpret_cast<const float4*>(s0 + q * 4);
    }

    #pragma unroll 1
    for (int p = p0; p < pend; ++p) {
        // ---- A) prefetch next phase's x ----
        if (p + 1 < pend) {
            const int pn = p + 1;
            const int cn = pn / 5;
            const int an = pn - cn * 5;
            const float* src = xb + cn * 4096 + an * 64;
            #pragma unroll
            for (int q = 0; q < 5; ++q)
                nxt[q] = *reinterpret_cast<const float4*>(src + q * 4);
        }

        // ---- B) unpack cur with wave-uniform constant offset ----
        float cf[20];
        #pragma unroll
        for (int q = 0; q < 5; ++q) {
            cf[4 * q + 0] = cur[q].x; cf[4 * q + 1] = cur[q].y;
            cf[4 * q + 2] = cur[q].z; cf[4 * q + 3] = cur[q].w;
        }
        float xv[17];
        if (off == 0) {
            #pragma unroll
            for (int t = 0; t < 17; ++t) xv[t] = cf[t];
        } else if (off == 1) {
            #pragma unroll
            for (int t = 0; t < 17; ++t) xv[t] = cf[t + 1];
        } else if (off == 2) {
            #pragma unroll
            for (int t = 0; t < 17; ++t) xv[t] = cf[t + 2];
        } else {
            #pragma unroll
            for (int t = 0; t < 17; ++t) xv[t] = cf[t + 3];
        }

        // ---- C) 25 taps, weights broadcast from LDS ----
        const int n0 = p * 5;                        // = c*25 + a*5
        #pragma unroll
        for (int b2 = 0; b2 < 5; ++b2) {
            const float  wlv = wl_s[n0 + b2];
            const float4 wp4 = *reinterpret_cast<const float4*>(&wp_s[(n0 + b2) * 4]);
            #pragma unroll
            for (int jj = 0; jj < 5; ++jj) {
                const float v = xv[3 * jj + b2];
                const float4 w4 = *reinterpret_cast<const float4*>(
                    &wu_s[(jj * 75 + n0 + b2) * 4]);
                ag[jj]    += v * wlv;
                au[0][jj] += v * w4.x;  au[1][jj] += v * w4.y;
                au[2][jj] += v * w4.z;  au[3][jj] += v * w4.w;
                ap[0][jj] += v * wp4.x; ap[1][jj] += v * wp4.y;
                ap[2][jj] += v * wp4.z; ap[3][jj] += v * wp4.w;
            }
        }

        // ---- D) rotate ----
        if (p + 1 < pend) {
            #pragma unroll
            for (int q = 0; q < 5; ++q) cur[q] = nxt[q];
        }
    }

    // ---- reduce: wave 1 publishes partials, wave 0 combines + epilogue ----
    if (wv == 1) {
        #pragma unroll
        for (int jj = 0; jj < 5; ++jj) {
            red4[jj * 64 + lane] =
                make_float4(au[0][jj], au[1][jj], au[2][jj], au[3][jj]);
            red4[(5 + jj) * 64 + lane] =
                make_float4(ap[0][jj], ap[1][jj], ap[2][jj], ap[3][jj]);
        }
        red4[10 * 64 + lane] = make_float4(ag[0], ag[1], ag[2], ag[3]);
        red4[11 * 64 + lane] = make_float4(ag[4], 0.f, 0.f, 0.f);
    }
    __syncthreads();
    if (wv == 0) {
        #pragma unroll
        for (int jj = 0; jj < 5; ++jj) {
            const float4 tu = red4[jj * 64 + lane];
            au[0][jj] += tu.x; au[1][jj] += tu.y;
            au[2][jj] += tu.z; au[3][jj] += tu.w;
            const float4 tp = red4[(5 + jj) * 64 + lane];
            ap[0][jj] += tp.x; ap[1][jj] += tp.y;
            ap[2][jj] += tp.z; ap[3][jj] += tp.w;
        }
        const float4 tg = red4[10 * 64 + lane];
        ag[0] += tg.x; ag[1] += tg.y; ag[2] += tg.z; ag[3] += tg.w;
        ag[4] += red4[11 * 64 + lane].x;

        const float bwl = b_wl[0];
        #pragma unroll
        for (int jj = 0; jj < 5; ++jj) {
            const int l = i * 20 + jgroup * 5 + jj;
            const float g = sigmoidf_(ag[jj] + bwl);
            #pragma unroll
            for (int o = 0; o < 4; ++o) {
                const float x1 = au[o][jj] + b_uc[o * 400 + l];
                const float x2 = ap[o][jj] + b_pc[o];
                y1t[(size_t)(o * 400 + l) * B + b0 + lane] =
                    fmaxf(x1 * g + x2 * (1.f - g), 0.f);
            }
        }
    }
}

// ------------- batch-last block kernel: wave owns one location l ----------
template<int CIN, int COUT, int K, int S, int OH, int IH, int VB>
__global__ __launch_bounds__(256)
void blockT_kernel(const float* __restrict__ in_t,
                   const float* __restrict__ w_uc,  // (L*LN, COUT)
                   const float* __restrict__ b_uc,  // (COUT*L)
                   const float* __restrict__ w_pc,  // (COUT, LN)
                   const float* __restrict__ b_pc,  // (COUT)
                   const float* __restrict__ w_wl,  // (LN)
                   const float* __restrict__ b_wl,  // (1)
                   float* __restrict__ out_t,
                   int B)
{
    constexpr int LN = CIN * K * K;
    constexpr int L  = OH * OH;
    const int wv   = threadIdx.x >> 6;
    const int lane = threadIdx.x & 63;
    const int l    = __builtin_amdgcn_readfirstlane(blockIdx.y * 4 + wv);
    if (l >= L) return;
    const int i = l / OH, j = l % OH;
    const int b = blockIdx.x * (64 * VB) + lane * VB;

    float au[COUT][VB], ap[COUT][VB], ag[VB];
    #pragma unroll
    for (int o = 0; o < COUT; ++o)
        #pragma unroll
        for (int q = 0; q < VB; ++q) { au[o][q] = 0.f; ap[o][q] = 0.f; }
    #pragma unroll
    for (int q = 0; q < VB; ++q) ag[q] = 0.f;

    const float* wu = w_uc + (size_t)l * LN * COUT;

    #pragma unroll
    for (int c = 0; c < CIN; ++c)
    #pragma unroll
    for (int a = 0; a < K; ++a)
    #pragma unroll
    for (int b2 = 0; b2 < K; ++b2) {
        const int n = c * K * K + a * K + b2;
        const int p = c * IH * IH + (i * S + a) * IH + (j * S + b2);
        float v[VB];
        const float* src = in_t + (size_t)p * B + b;
        if constexpr (VB == 4) {
            const float4 t = *reinterpret_cast<const float4*>(src);
            v[0] = t.x; v[1] = t.y; v[2] = t.z; v[3] = t.w;
        } else if constexpr (VB == 2) {
            const float2 t = *reinterpret_cast<const float2*>(src);
            v[0] = t.x; v[1] = t.y;
        } else {
            v[0] = src[0];
        }
        const float wl = w_wl[n];
        #pragma unroll
        for (int q = 0; q < VB; ++q) ag[q] += v[q] * wl;
        #pragma unroll
        for (int o = 0; o < COUT; ++o) {
            const float wuv = wu[n * COUT + o];
            const float wpv = w_pc[o * LN + n];
            #pragma unroll
            for (int q = 0; q < VB; ++q) {
                au[o][q] += v[q] * wuv;
                ap[o][q] += v[q] * wpv;
            }
        }
    }

    const float bwl = b_wl[0];
    float g[VB];
    #pragma unroll
    for (int q = 0; q < VB; ++q) g[q] = sigmoidf_(ag[q] + bwl);

    #pragma unroll
    for (int o = 0; o < COUT; ++o) {
        const float buc = b_uc[o * L + l];
        const float bpc = b_pc[o];
        float y[VB];
        #pragma unroll
        for (int q = 0; q < VB; ++q) {
            const float x1 = au[o][q] + buc;
            const float x2 = ap[o][q] + bpc;
            y[q] = fmaxf(x1 * g[q] + x2 * (1.f - g[q]), 0.f);
        }
        float* dst = out_t + (size_t)(o * L + l) * B + b;
        if constexpr (VB == 4) {
            float4 t; t.x = y[0]; t.y = y[1]; t.z = y[2]; t.w = y[3];
            *reinterpret_cast<float4*>(dst) = t;
        } else if constexpr (VB == 2) {
            float2 t; t.x = y[0]; t.y = y[1];
            *reinterpret_cast<float2*>(dst) = t;
        } else {
            dst[0] = y[0];
        }
    }
}

// ---------- block3 split-channel: cin=6,cout=16,k=3,s=2,oh=4,ih=9 ----------
// grid (B/64, 8), 256 threads (4 waves). Wave w: l = blockIdx.y*2 + (w>>1),
// channels [3*(w&1), 3*(w&1)+3). Partials reduced via LDS; c-half-0 waves
// do the gate blend + ReLU epilogue.
__global__ __launch_bounds__(256)
void block3T_split(const float* __restrict__ in_t,  // (486, B)
                   const float* __restrict__ w_uc,  // (16*54, 16)
                   const float* __restrict__ b_uc,  // (16*16)
                   const float* __restrict__ w_pc,  // (16, 54)
                   const float* __restrict__ b_pc,  // (16)
                   const float* __restrict__ w_wl,  // (54)
                   const float* __restrict__ b_wl,  // (1)
                   float* __restrict__ out_t,       // (256, B)
                   int B)
{
    __shared__ __align__(16) float4 red4[2][9][64];

    const int tid   = threadIdx.x;
    const int lane  = tid & 63;
    const int w     = __builtin_amdgcn_readfirstlane(tid >> 6);  // 0..3
    const int lslot = w >> 1;
    const int chalf = w & 1;
    const int l     = blockIdx.y * 2 + lslot;        // 0..15
    const int i     = l >> 2, j = l & 3;
    const int b     = blockIdx.x * 64 + lane;

    float au[16], ap[16], ag = 0.f;
    #pragma unroll
    for (int o = 0; o < 16; ++o) { au[o] = 0.f; ap[o] = 0.f; }

    const float* wu = w_uc + (size_t)l * 54 * 16;
    #pragma unroll
    for (int cc = 0; cc < 3; ++cc) {
        const int c = chalf * 3 + cc;
        #pragma unroll
        for (int a = 0; a < 3; ++a)
        #pragma unroll
        for (int b2 = 0; b2 < 3; ++b2) {
            const int n = c * 9 + a * 3 + b2;
            const int p = c * 81 + (i * 2 + a) * 9 + (j * 2 + b2);
            const float v = in_t[(size_t)p * B + b];
            ag += v * w_wl[n];
            #pragma unroll
            for (int o = 0; o < 16; ++o) {
                au[o] += v * wu[n * 16 + o];
                ap[o] += v * w_pc[o * 54 + n];
            }
        }
    }

    if (chalf == 1) {
        #pragma unroll
        for (int q = 0; q < 4; ++q) {
            red4[lslot][q][lane] =
                make_float4(au[4*q], au[4*q+1], au[4*q+2], au[4*q+3]);
            red4[lslot][4 + q][lane] =
                make_float4(ap[4*q], ap[4*q+1], ap[4*q+2], ap[4*q+3]);
        }
        red4[lslot][8][lane] = make_float4(ag, 0.f, 0.f, 0.f);
    }
    __syncthreads();
    if (chalf == 0) {
        #pragma unroll
        for (int q = 0; q < 4; ++q) {
            const float4 tu = red4[lslot][q][lane];
            au[4*q] += tu.x; au[4*q+1] += tu.y; au[4*q+2] += tu.z; au[4*q+3] += tu.w;
            const float4 tp = red4[lslot][4 + q][lane];
            ap[4*q] += tp.x; ap[4*q+1] += tp.y; ap[4*q+2] += tp.z; ap[4*q+3] += tp.w;
        }
        ag += red4[lslot][8][lane].x;

        const float g = sigmoidf_(ag + b_wl[0]);
        #pragma unroll
        for (int o = 0; o < 16; ++o) {
            const float x1 = au[o] + b_uc[o * 16 + l];
            const float x2 = ap[o] + b_pc[o];
            out_t[(size_t)(o * 16 + l) * B + b] =
                fmaxf(x1 * g + x2 * (1.f - g), 0.f);
        }
    }
}

// ---------- block4 (cin=16,k=3,s=2,oh=1,cout=32) + FC(32->4), batch-last ---
__global__ __launch_bounds__(256)
void block4T_fc(const float* __restrict__ in_t,  // (256, B)
                const float* __restrict__ w_uc,  // (144,32)
                const float* __restrict__ b_uc,  // (32)
                const float* __restrict__ w_pc,  // (32,144)
                const float* __restrict__ b_pc,  // (32)
                const float* __restrict__ w_wl,  // (144)
                const float* __restrict__ b_wl,  // (1)
                const float* __restrict__ fc_w,  // (32,4)
                const float* __restrict__ fc_b,  // (4)
                float* __restrict__ out,         // (B,4)
                int B)
{
    __shared__ __align__(16) float wu_s[144 * 36];
    __shared__ __align__(16) float wp_s[144 * 36];
    __shared__ float wl_s[144];
    __shared__ float buc_s[32], bpc_s[32], fcw_s[128], fcb_s[4];
    __shared__ float red[4][64][5];

    const int tid  = threadIdx.x;
    const int wv   = tid >> 6;
    const int lane = tid & 63;
    const int o0   = __builtin_amdgcn_readfirstlane(wv * 8);
    const int b    = blockIdx.x * 64 + lane;

    for (int idx = tid; idx < 144 * 32; idx += 256) {
        wu_s[(idx >> 5) * 36 + (idx & 31)] = w_uc[idx];
        const int o = idx / 144, n = idx - o * 144;
        wp_s[n * 36 + o] = w_pc[idx];
    }
    if (tid < 144) wl_s[tid] = w_wl[tid];
    if (tid < 32)  { buc_s[tid] = b_uc[tid]; bpc_s[tid] = b_pc[tid]; }
    if (tid >= 64 && tid < 192) fcw_s[tid - 64] = fc_w[tid - 64];
    if (tid >= 192 && tid < 196) fcb_s[tid - 192] = fc_b[tid - 192];
    __syncthreads();

    float au[8], apc[8], ag = 0.f;
    #pragma unroll
    for (int oo = 0; oo < 8; ++oo) { au[oo] = 0.f; apc[oo] = 0.f; }

    #pragma unroll
    for (int c = 0; c < 16; ++c) {
        float v[9];
        #pragma unroll
        for (int a = 0; a < 3; ++a)
        #pragma unroll
        for (int b2 = 0; b2 < 3; ++b2)
            v[a * 3 + b2] = in_t[(size_t)(c * 16 + a * 4 + b2) * B + b];

        #pragma unroll
        for (int t = 0; t < 9; ++t) {
            const int n = c * 9 + t;
            ag += v[t] * wl_s[n];
            const float4 wuA = *reinterpret_cast<const float4*>(&wu_s[n * 36 + o0]);
            const float4 wuB = *reinterpret_cast<const float4*>(&wu_s[n * 36 + o0 + 4]);
            const float4 wpA = *reinterpret_cast<const float4*>(&wp_s[n * 36 + o0]);
            const float4 wpB = *reinterpret_cast<const float4*>(&wp_s[n * 36 + o0 + 4]);
            au[0] += v[t] * wuA.x;  au[1] += v[t] * wuA.y;
            au[2] += v[t] * wuA.z;  au[3] += v[t] * wuA.w;
            au[4] += v[t] * wuB.x;  au[5] += v[t] * wuB.y;
            au[6] += v[t] * wuB.z;  au[7] += v[t] * wuB.w;
            apc[0] += v[t] * wpA.x; apc[1] += v[t] * wpA.y;
            apc[2] += v[t] * wpA.z; apc[3] += v[t] * wpA.w;
            apc[4] += v[t] * wpB.x; apc[5] += v[t] * wpB.y;
            apc[6] += v[t] * wpB.z; apc[7] += v[t] * wpB.w;
        }
    }

    const float g = sigmoidf_(ag + b_wl[0]);
    float pf[4] = {0.f, 0.f, 0.f, 0.f};
    #pragma unroll
    for (int oo = 0; oo < 8; ++oo) {
        const int o = o0 + oo;
        const float h = fmaxf((au[oo] + buc_s[o]) * g +
                              (apc[oo] + bpc_s[o]) * (1.f - g), 0.f);
        #pragma unroll
        for (int f = 0; f < 4; ++f) pf[f] += h * fcw_s[o * 4 + f];
    }
    #pragma unroll
    for (int f = 0; f < 4; ++f) red[wv][lane][f] = pf[f];
    __syncthreads();
    if (wv == 0) {
        float4 s;
        s.x = fcb_s[0] + red[0][lane][0] + red[1][lane][0] + red[2][lane][0] + red[3][lane][0];
        s.y = fcb_s[1] + red[0][lane][1] + red[1][lane][1] + red[2][lane][1] + red[3][lane][1];
        s.z = fcb_s[2] + red[0][lane][2] + red[1][lane][2] + red[2][lane][2] + red[3][lane][2];
        s.w = fcb_s[3] + red[0][lane][3] + red[1][lane][3] + red[2][lane][3] + red[3][lane][3];
        *reinterpret_cast<float4*>(out + (size_t)b * 4) = s;
    }
}

// ======================= fallback path (round-1, NCHW) ====================
template<int CIN, int COUT, int K, int S, int OH, int IH, int BPB>
__global__ __launch_bounds__(256)
void block_kernel(const float* __restrict__ in,
                  const float* __restrict__ w_uc,
                  const float* __restrict__ b_uc,
                  const float* __restrict__ w_pc,
                  const float* __restrict__ b_pc,
                  const float* __restrict__ w_wl,
                  const float* __restrict__ b_wl,
                  float* __restrict__ out,
                  int B)
{
    constexpr int LN   = CIN * K * K;
    constexpr int L    = OH * OH;
    constexpr int TILE = CIN * IH * IH;
    __shared__ __align__(16) float lds[BPB * TILE];

    const int b0 = blockIdx.x * BPB;
    const int nb = (B - b0 < BPB) ? (B - b0) : BPB;
    const int tot = nb * TILE;
    const float* src = in + (size_t)b0 * TILE;
    if ((tot & 3) == 0) {
        const float4* s4 = reinterpret_cast<const float4*>(src);
        float4* d4 = reinterpret_cast<float4*>(lds);
        for (int idx = threadIdx.x; idx < (tot >> 2); idx += blockDim.x) d4[idx] = s4[idx];
    } else {
        for (int idx = threadIdx.x; idx < tot; idx += blockDim.x) lds[idx] = src[idx];
    }
    __syncthreads();

    const float bwl = b_wl[0];
    for (int t = threadIdx.x; t < nb * L; t += blockDim.x) {
        const int bb = t / L;
        const int l  = t % L;
        const int i  = l / OH, j = l % OH;
        const float* tile = lds + bb * TILE;

        float acc_uc[COUT], acc_pc[COUT];
        #pragma unroll
        for (int o = 0; o < COUT; ++o) { acc_uc[o] = 0.f; acc_pc[o] = 0.f; }
        float acc_g = 0.f;

        const float* wu = w_uc + (size_t)l * LN * COUT;
        #pragma unroll
        for (int c = 0; c < CIN; ++c)
        #pragma unroll
        for (int a = 0; a < K; ++a)
        #pragma unroll
        for (int b2 = 0; b2 < K; ++b2) {
            const int n = c * K * K + a * K + b2;
            const float v = tile[c * IH * IH + (i * S + a) * IH + (j * S + b2)];
            acc_g += v * w_wl[n];
            #pragma unroll
            for (int o = 0; o < COUT; ++o) acc_uc[o] += v * wu[n * COUT + o];
            #pragma unroll
            for (int o = 0; o < COUT; ++o) acc_pc[o] += v * w_pc[o * LN + n];
        }

        const float g = sigmoidf_(acc_g + bwl);
        const size_t ob = (size_t)(b0 + bb) * COUT * L;
        #pragma unroll
        for (int o = 0; o < COUT; ++o) {
            const float x1 = acc_uc[o] + b_uc[o * L + l];
            const float x2 = acc_pc[o] + b_pc[o];
            out[ob + o * L + l] = fmaxf(x1 * g + x2 * (1.f - g), 0.f);
        }
    }
}

__global__ __launch_bounds__(256)
void block4_fc_kernel(const float* __restrict__ in,
                      const float* __restrict__ w_uc,
                      const float* __restrict__ b_uc,
                      const float* __restrict__ w_pc,
                      const float* __restrict__ b_pc,
                      const float* __restrict__ w_wl,
                      const float* __restrict__ b_wl,
                      const float* __restrict__ fc_w,
                      const float* __restrict__ fc_b,
                      float* __restrict__ out,
                      int B)
{
    __shared__ float hbuf[8][32];
    const int bl = threadIdx.x >> 5;
    const int o  = threadIdx.x & 31;
    const int b  = blockIdx.x * 8 + bl;

    if (b < B) {
        const float* xb = in + (size_t)b * 256;
        float acc_uc = 0.f, acc_pc = 0.f, acc_g = 0.f;
        #pragma unroll
        for (int c = 0; c < 16; ++c)
        #pragma unroll
        for (int a = 0; a < 3; ++a)
        #pragma unroll
        for (int b2 = 0; b2 < 3; ++b2) {
            const int n = c * 9 + a * 3 + b2;
            const float v = xb[c * 16 + a * 4 + b2];
            acc_uc += v * w_uc[n * 32 + o];
            acc_pc += v * w_pc[o * 144 + n];
            acc_g  += v * w_wl[n];
        }
        const float g  = sigmoidf_(acc_g + b_wl[0]);
        hbuf[bl][o] = fmaxf((acc_uc + b_uc[o]) * g + (acc_pc + b_pc[o]) * (1.f - g), 0.f);
    }
    __syncthreads();

    if (threadIdx.x < 32) {
        const int bl2 = threadIdx.x >> 2;
        const int f   = threadIdx.x & 3;
        const int bb  = blockIdx.x * 8 + bl2;
        if (bb < B) {
            float s = fc_b[f];
            #pragma unroll
            for (int oo = 0; oo < 32; ++oo) s += hbuf[bl2][oo] * fc_w[oo * 4 + f];
            out[(size_t)bb * 4 + f] = s;
        }
    }
}

// ==========================================================================
extern "C" void kernel_launch(void* const* d_in, const int* in_sizes, int n_in,
                              void* d_out, int out_size, void* d_ws, size_t ws_size,
                              hipStream_t stream) {
    const float* x    = (const float*)d_in[0];
    const float* wuc1 = (const float*)d_in[1];
    const float* buc1 = (const float*)d_in[2];
    const float* wpc1 = (const float*)d_in[3];
    const float* bpc1 = (const float*)d_in[4];
    const float* wwl1 = (const float*)d_in[5];
    const float* bwl1 = (const float*)d_in[6];
    const float* wuc2 = (const float*)d_in[7];
    const float* buc2 = (const float*)d_in[8];
    const float* wpc2 = (const float*)d_in[9];
    const float* bpc2 = (const float*)d_in[10];
    const float* wwl2 = (const float*)d_in[11];
    const float* bwl2 = (const float*)d_in[12];
    const float* wuc3 = (const float*)d_in[13];
    const float* buc3 = (const float*)d_in[14];
    const float* wpc3 = (const float*)d_in[15];
    const float* bpc3 = (const float*)d_in[16];
    const float* wwl3 = (const float*)d_in[17];
    const float* bwl3 = (const float*)d_in[18];
    const float* wuc4 = (const float*)d_in[19];
    const float* buc4 = (const float*)d_in[20];
    const float* wpc4 = (const float*)d_in[21];
    const float* bpc4 = (const float*)d_in[22];
    const float* wwl4 = (const float*)d_in[23];
    const float* bwl4 = (const float*)d_in[24];
    const float* fcw  = (const float*)d_in[25];
    const float* fcb  = (const float*)d_in[26];

    const int B = in_sizes[0] / (3 * 64 * 64);   // 2048
    float* ws = (float*)d_ws;
    const size_t need = sizeof(float) * (size_t)(1600 + 486 + 256) * B;

    if (ws_size >= need && (B % 256) == 0) {
        // ---------------- batch-last fast path (round-17 best) ------------
        float* y1 = ws;                             // (1600, B)
        float* y2 = y1 + (size_t)1600 * B;          // (486, B)
        float* y3 = y2 + (size_t)486 * B;           // (256, B)

        block1_fused9<<<dim3(B / 64, 80), 128, 0, stream>>>(
            x, wuc1, buc1, wpc1, bpc1, wwl1, bwl1, y1, B);
        blockT_kernel<4, 6, 3, 2, 9, 20, 1>
            <<<dim3(B / 64, 21), 256, 0, stream>>>(y1, wuc2, buc2, wpc2, bpc2, wwl2, bwl2, y2, B);
        block3T_split<<<dim3(B / 64, 8), 256, 0, stream>>>(
            y2, wuc3, buc3, wpc3, bpc3, wwl3, bwl3, y3, B);
        block4T_fc<<<B / 64, 256, 0, stream>>>(y3, wuc4, buc4, wpc4, bpc4, wwl4, bwl4,
                                               fcw, fcb, (float*)d_out, B);
    } else {
        // ---------------- fallback (round-1) ----------------
        float* y1 = ws;
        float* y2 = y1 + (size_t)B * 4 * 400;
        float* y3 = y2 + (size_t)B * 6 * 81;
        block_kernel<3, 4, 5, 3, 20, 64, 1>
            <<<B, 256, 0, stream>>>(x, wuc1, buc1, wpc1, bpc1, wwl1, bwl1, y1, B);
        block_kernel<4, 6, 3, 2, 9, 20, 4>
            <<<(B + 3) / 4, 256, 0, stream>>>(y1, wuc2, buc2, wpc2, bpc2, wwl2, bwl2, y2, B);
        block_kernel<6, 16, 3, 2, 4, 9, 16>
            <<<(B + 15) / 16, 256, 0, stream>>>(y2, wuc3, buc3, wpc3, bpc3, wwl3, bwl3, y3, B);
        block4_fc_kernel<<<(B + 7) / 8, 256, 0, stream>>>(
            y3, wuc4, buc4, wpc4, bpc4, wwl4, bwl4, fcw, fcb, (float*)d_out, B);
    }
}